// Round 1
// baseline (9375.655 us; speedup 1.0000x reference)
//
#include <hip/hip_runtime.h>
#include <hip/hip_bf16.h>

// LSTM fused persistent kernel for MI355X (gfx950).
// B=64, T=1024, D=512, H=512. One kernel, 64 blocks, custom grid barrier/step.

#define BB   64
#define TT   1024
#define DD   512
#define HH   512
#define NBLK 64     // persistent blocks (<= 256 CUs -> all co-resident)
#define JPB  8      // h-columns owned per block (64*8 = 512)
#define NTHR 256    // 4 waves

typedef float  f32x4  __attribute__((ext_vector_type(4)));
typedef __bf16 bf16x8 __attribute__((ext_vector_type(8)));
typedef __bf16 bf16x4 __attribute__((ext_vector_type(4)));

__device__ __forceinline__ float sigf(float v)   { return 1.f / (1.f + __expf(-v)); }
__device__ __forceinline__ float tanh_f(float v) { return 2.f / (1.f + __expf(-2.f * v)) - 1.f; }

// Monotonic-counter grid barrier. Agent-scope release/acquire gives cross-XCD
// visibility for the h double-buffer (per-XCD L2s are not coherent).
__device__ __forceinline__ void gsync(int* bar, int& gen) {
  __syncthreads();
  if (threadIdx.x == 0) {
    gen += NBLK;
    __hip_atomic_fetch_add(bar, 1, __ATOMIC_RELEASE, __HIP_MEMORY_SCOPE_AGENT);
    while (__hip_atomic_load(bar, __ATOMIC_ACQUIRE, __HIP_MEMORY_SCOPE_AGENT) < gen) {
      __builtin_amdgcn_s_sleep(1);
    }
  }
  __syncthreads();
}

__global__ __launch_bounds__(NTHR) void lstm_fused(
    const float* __restrict__ x,
    const float* __restrict__ Wc, const float* __restrict__ Wi,
    const float* __restrict__ Wf, const float* __restrict__ Wo,
    const float* __restrict__ Uc, const float* __restrict__ Ui,
    const float* __restrict__ Uf, const float* __restrict__ Uo,
    const float* __restrict__ bc, const float* __restrict__ bi,
    const float* __restrict__ bfv, const float* __restrict__ bo,
    float* __restrict__ out,
    __bf16* hb0, __bf16* hb1, int* bar, __bf16* xbf, int use_xbf)
{
  // WU[n][k]: n in [0,32) gate-col (gate = n&3 in {c,i,f,o}, jloc = n>>2),
  // k in [0,1024): k<512 -> W_gate[k][j], else U_gate[k-512][j]. bf16, 64 KiB.
  // Byte offsets XOR-swizzled with ((n&7)<<4) -> <=2-way bank conflict (free).
  __shared__ __bf16 WU[32 * 1024];

  const int tid = threadIdx.x;
  const int w   = tid >> 6;      // wave id: batch tile
  const int l   = tid & 63;
  const int l15 = l & 15;
  const int l4  = l >> 4;
  const int j0  = blockIdx.x * JPB;

  // ---- one-time: stage W/U slice into LDS ----
  for (int idx = tid; idx < 32 * 1024; idx += NTHR) {
    int n = idx & 31;
    int k = idx >> 5;
    int g = n & 3;
    int j = j0 + (n >> 2);
    const float* Wg = (g == 0) ? Wc : (g == 1) ? Wi : (g == 2) ? Wf : Wo;
    const float* Ug = (g == 0) ? Uc : (g == 1) ? Ui : (g == 2) ? Uf : Uo;
    float v = (k < DD) ? Wg[k * HH + j] : Ug[(k - DD) * HH + j];
    int off = ((n << 11) + (k << 1)) ^ ((n & 7) << 4);
    *reinterpret_cast<__bf16*>(reinterpret_cast<char*>(WU) + off) = (__bf16)v;
  }

  // ---- one-time: cast x to bf16 in workspace (if it fits) ----
  if (use_xbf) {
    const f32x4* xs = reinterpret_cast<const f32x4*>(x);
    bf16x4* xd = reinterpret_cast<bf16x4*>(xbf);
    const int total = BB * TT * DD / 4;
    for (int i = blockIdx.x * NTHR + tid; i < total; i += NBLK * NTHR) {
      f32x4 v = xs[i];
      bf16x4 o;
      o[0] = (__bf16)v[0]; o[1] = (__bf16)v[1];
      o[2] = (__bf16)v[2]; o[3] = (__bf16)v[3];
      xd[i] = o;
    }
  }

  int gen = 0;
  gsync(bar, gen);   // WU staged (block-local) + xbf + zeroed h visible

  // ---- per-lane constants ----
  // GEMM: D[M=32 gatecols][N=64 batch] = WU^T (A) x xh (B), K=1024.
  // A-frag (m-tile mt): lane holds A[mt*16 + l15][kk*32 + l4*8 + e]
  // B-frag:             lane holds B[kk*32 + l4*8 + e][w*16 + l15]
  // C: row(M) = (l>>4)*4 + r, col(N) = l15  => gate = r, jloc = mt*4 + l4.
  const int brow = w * 16 + l15;              // batch row (B-frag col & C col)
  const int koff = l4 * 8;
  const int baseA = (l15 << 11) + (koff << 1);  // unswizzled LDS byte offset
  const int swzA  = (l15 & 7) << 4;
  const char* WUc = reinterpret_cast<const char*>(WU);

  const int jA = j0 + l4;       // mt=0 column
  const int jB = jA + 4;        // mt=1 column
  const float bc0 = bc[jA], bi0 = bi[jA], bf0 = bfv[jA], bo0 = bo[jA];
  const float bc1 = bc[jB], bi1 = bi[jB], bf1 = bfv[jB], bo1 = bo[jB];

  const size_t xbase = (size_t)brow * TT * DD + koff;
  const size_t obase = (size_t)brow * TT * HH;
  const int    hbase = brow * HH + koff;
  const int    hsA   = brow * HH + jA;
  const int    hsB   = brow * HH + jB;

  __bf16* hcur = hb0;
  __bf16* hnxt = hb1;
  float c0 = 0.f, c1 = 0.f;

  for (int t = 0; t < TT; ++t) {
    f32x4 acc0 = {0.f, 0.f, 0.f, 0.f};
    f32x4 acc1 = {0.f, 0.f, 0.f, 0.f};

    // K = 0..511 : x part
    if (use_xbf) {
      const __bf16* xrow = xbf + xbase + (size_t)t * DD;
      #pragma unroll
      for (int kk = 0; kk < 16; ++kk) {
        bf16x8 bfr = *reinterpret_cast<const bf16x8*>(xrow + kk * 32);
        int oA = (baseA + (kk << 6)) ^ swzA;
        bf16x8 a0 = *reinterpret_cast<const bf16x8*>(WUc + oA);
        bf16x8 a1 = *reinterpret_cast<const bf16x8*>(WUc + oA + 32768);
        acc0 = __builtin_amdgcn_mfma_f32_16x16x32_bf16(a0, bfr, acc0, 0, 0, 0);
        acc1 = __builtin_amdgcn_mfma_f32_16x16x32_bf16(a1, bfr, acc1, 0, 0, 0);
      }
    } else {
      const float* xrow = x + xbase + (size_t)t * DD;
      #pragma unroll
      for (int kk = 0; kk < 16; ++kk) {
        f32x4 f0 = *reinterpret_cast<const f32x4*>(xrow + kk * 32);
        f32x4 f1 = *reinterpret_cast<const f32x4*>(xrow + kk * 32 + 4);
        bf16x8 bfr;
        bfr[0] = (__bf16)f0[0]; bfr[1] = (__bf16)f0[1];
        bfr[2] = (__bf16)f0[2]; bfr[3] = (__bf16)f0[3];
        bfr[4] = (__bf16)f1[0]; bfr[5] = (__bf16)f1[1];
        bfr[6] = (__bf16)f1[2]; bfr[7] = (__bf16)f1[3];
        int oA = (baseA + (kk << 6)) ^ swzA;
        bf16x8 a0 = *reinterpret_cast<const bf16x8*>(WUc + oA);
        bf16x8 a1 = *reinterpret_cast<const bf16x8*>(WUc + oA + 32768);
        acc0 = __builtin_amdgcn_mfma_f32_16x16x32_bf16(a0, bfr, acc0, 0, 0, 0);
        acc1 = __builtin_amdgcn_mfma_f32_16x16x32_bf16(a1, bfr, acc1, 0, 0, 0);
      }
    }

    // K = 512..1023 : h part (bf16 double buffer in ws)
    {
      const __bf16* hrow = hcur + hbase;
      #pragma unroll
      for (int kk = 0; kk < 16; ++kk) {
        bf16x8 bfr = *reinterpret_cast<const bf16x8*>(hrow + kk * 32);
        int oA = (baseA + 1024 + (kk << 6)) ^ swzA;
        bf16x8 a0 = *reinterpret_cast<const bf16x8*>(WUc + oA);
        bf16x8 a1 = *reinterpret_cast<const bf16x8*>(WUc + oA + 32768);
        acc0 = __builtin_amdgcn_mfma_f32_16x16x32_bf16(a0, bfr, acc0, 0, 0, 0);
        acc1 = __builtin_amdgcn_mfma_f32_16x16x32_bf16(a1, bfr, acc1, 0, 0, 0);
      }
    }

    // epilogue: 4 gate regs per lane per m-tile -> c,h update (c in registers)
    {
      float a = tanh_f(acc0[0] + bc0);
      float i = sigf  (acc0[1] + bi0);
      float f = sigf  (acc0[2] + bf0);
      float o = sigf  (acc0[3] + bo0);
      c0 = i * a + f * c0;
      float h = o * tanh_f(c0);
      hnxt[hsA] = (__bf16)h;
      out[obase + (size_t)t * HH + jA] = h;
    }
    {
      float a = tanh_f(acc1[0] + bc1);
      float i = sigf  (acc1[1] + bi1);
      float f = sigf  (acc1[2] + bf1);
      float o = sigf  (acc1[3] + bo1);
      c1 = i * a + f * c1;
      float h = o * tanh_f(c1);
      hnxt[hsB] = (__bf16)h;
      out[obase + (size_t)t * HH + jB] = h;
    }

    gsync(bar, gen);                 // publish h_{t} before anyone reads it
    __bf16* tmp = hcur; hcur = hnxt; hnxt = tmp;
  }
}

extern "C" void kernel_launch(void* const* d_in, const int* in_sizes, int n_in,
                              void* d_out, int out_size, void* d_ws, size_t ws_size,
                              hipStream_t stream) {
  const float* x   = (const float*)d_in[0];
  const float* Wc  = (const float*)d_in[1];
  const float* Wi  = (const float*)d_in[2];
  const float* Wf  = (const float*)d_in[3];
  const float* Wo  = (const float*)d_in[4];
  const float* Uc  = (const float*)d_in[5];
  const float* Ui  = (const float*)d_in[6];
  const float* Uf  = (const float*)d_in[7];
  const float* Uo  = (const float*)d_in[8];
  const float* bc  = (const float*)d_in[9];
  const float* bi  = (const float*)d_in[10];
  const float* bfv = (const float*)d_in[11];
  const float* bo  = (const float*)d_in[12];
  float* out = (float*)d_out;

  char* ws = (char*)d_ws;
  __bf16* hb0 = (__bf16*)ws;                       //  65536 B
  __bf16* hb1 = (__bf16*)(ws + 65536);             //  65536 B
  int*    bar = (int*)(ws + 131072);               //  counter
  __bf16* xbf = (__bf16*)(ws + 131584);            //  64 MiB optional
  const size_t need_xbf = 131584ull + (size_t)BB * TT * DD * 2ull;
  int use_xbf = (ws_size >= need_xbf) ? 1 : 0;

  size_t zbytes = 131328;
  if (zbytes > ws_size) zbytes = ws_size;
  hipMemsetAsync(d_ws, 0, zbytes, stream);         // zero h buffers + barrier

  lstm_fused<<<dim3(NBLK), dim3(NTHR), 0, stream>>>(
      x, Wc, Wi, Wf, Wo, Uc, Ui, Uf, Uo, bc, bi, bfv, bo,
      out, hb0, hb1, bar, xbf, use_xbf);
}